// Round 6
// baseline (238.737 us; speedup 1.0000x reference)
//
#include <hip/hip_runtime.h>

typedef short short4v __attribute__((ext_vector_type(4)));
typedef short short8 __attribute__((ext_vector_type(8)));
typedef float floatx4 __attribute__((ext_vector_type(4)));
typedef unsigned int uint;
typedef unsigned short ushort;

#define CH 512
#define NN 2048
#define DD 128
#define RSCALE 0.08838834764831845f  // 1/sqrt(128)

__device__ __forceinline__ float bf2f(ushort u) {
    union { uint i; float f; } v; v.i = ((uint)u) << 16; return v.f;
}
__device__ __forceinline__ ushort f2bf(float f) {
    union { float f; uint u; } v; v.f = f;
    uint u = v.u;
    return (ushort)((u + 0x7fffu + ((u >> 16) & 1u)) >> 16);
}

// ---------------------------------------------------------------------------
// K0: weights -> bf16 AND zero lsum AND zero out (merged; one launch).
// ---------------------------------------------------------------------------
__global__ __launch_bounds__(256) void k0_prep(
    const float* __restrict__ wqk, const float* __restrict__ wv,
    ushort* __restrict__ Wbf, float* __restrict__ lsum,
    float* __restrict__ out)
{
    int gid = blockIdx.x * 256 + threadIdx.x;
    if (gid < 32768) {
        int base = gid * 4;
        const float* src = (base < 65536) ? (wqk + base) : (wv + base - 65536);
        float4 v = *(const float4*)src;
        short4v o;
        o[0] = (short)f2bf(v.x); o[1] = (short)f2bf(v.y);
        o[2] = (short)f2bf(v.z); o[3] = (short)f2bf(v.w);
        *(short4v*)&Wbf[base] = o;
    }
    if (gid < 16384) lsum[gid] = 0.0f;
    float4 z; z.x = 0.f; z.y = 0.f; z.z = 0.f; z.w = 0.f;
#pragma unroll
    for (int i = 0; i < 4; i++)
        *(float4*)&out[(size_t)(gid + i * 131072) * 4] = z;
}

// ---------------------------------------------------------------------------
// K1: projections, d-stack split across h; c-step 64 (8 iterations, half the
// barriers of the c-step-32 version). Pads 72 (conflict-free b128 phases).
// Grid (64 nt, 2 h, 8 b) = 1024 blocks. LDS 33280 -> 4 blocks/CU.
// ---------------------------------------------------------------------------
__global__ __launch_bounds__(256) void k1_proj(
    const float* __restrict__ x,
    const ushort* __restrict__ Wbf,
    const float* __restrict__ bv,
    ushort* __restrict__ Q,
    ushort* __restrict__ VT)
{
    const int nt = blockIdx.x;   // 0..63
    const int h  = blockIdx.y;   // 0..1 (0: Q rows, 1: V rows)
    const int b  = blockIdx.z;   // 0..7
    const int n0 = nt * 32;
    const int t = threadIdx.x;
    const int lane = t & 63, w = t >> 6, l15 = lane & 15, quad = lane >> 4;

    __shared__ __attribute__((aligned(16))) ushort As[32 * 72];
    __shared__ __attribute__((aligned(16))) ushort Bs[128 * 72];
    __shared__ __attribute__((aligned(16))) ushort Vt[128 * 40];

    floatx4 acc[2][2];
#pragma unroll
    for (int i = 0; i < 2; i++)
#pragma unroll
        for (int j = 0; j < 2; j++) acc[i][j] = (floatx4)(0.0f);

    const float* xb = x + b * (CH * NN) + n0;
    const ushort* Wh = Wbf + h * 128 * CH;

    const int an = t & 31, ag = t >> 5;       // A-stage: n, c-chunk (0..7)

    for (int c0 = 0; c0 < CH; c0 += 64) {
        // stage A: [32 n][64 c], fp32 -> bf16, 8 elems/thread
        {
            short8 v;
#pragma unroll
            for (int i = 0; i < 8; i++)
                v[i] = (short)f2bf(xb[(c0 + ag * 8 + i) * NN + an]);
            *(short8*)&As[an * 72 + ag * 8] = v;
        }
        // stage B: [128 rows][64 c], 4 x b128/thread
#pragma unroll
        for (int rep = 0; rep < 4; rep++) {
            int idx = rep * 256 + t;
            int row = idx >> 3, g = idx & 7;
            *(short8*)&Bs[row * 72 + g * 8] = *(const short8*)&Wh[row * CH + c0 + g * 8];
        }
        __syncthreads();
#pragma unroll
        for (int kd = 0; kd < 2; kd++) {
            short8 a0 = *(short8*)&As[(l15) * 72 + kd * 32 + quad * 8];
            short8 a1 = *(short8*)&As[(16 + l15) * 72 + kd * 32 + quad * 8];
#pragma unroll
            for (int dt2 = 0; dt2 < 2; dt2++) {
                short8 bf = *(short8*)&Bs[(w * 32 + dt2 * 16 + l15) * 72 + kd * 32 + quad * 8];
                acc[0][dt2] = __builtin_amdgcn_mfma_f32_16x16x32_bf16(a0, bf, acc[0][dt2], 0, 0, 0);
                acc[1][dt2] = __builtin_amdgcn_mfma_f32_16x16x32_bf16(a1, bf, acc[1][dt2], 0, 0, 0);
            }
        }
        __syncthreads();
    }

    // epilogue
#pragma unroll
    for (int ns = 0; ns < 2; ns++)
#pragma unroll
        for (int dt2 = 0; dt2 < 2; dt2++) {
            int ds_ = w * 32 + dt2 * 16 + l15;  // 0..127
#pragma unroll
            for (int r = 0; r < 4; r++) {
                int nl = ns * 16 + quad * 4 + r;
                float val = acc[ns][dt2][r];
                if (h == 0) {
                    Q[b * (NN * DD) + (n0 + nl) * DD + ds_] = f2bf(val);
                } else {
                    Vt[ds_ * 40 + nl] = f2bf(val + bv[ds_]);
                }
            }
        }
    if (h == 1) {
        __syncthreads();
#pragma unroll
        for (int rep = 0; rep < 2; rep++) {
            int idx = rep * 256 + t;
            int dv = idx >> 2, seg = idx & 3;
            *(short8*)&VT[((size_t)b * DD + dv) * NN + n0 + seg * 8] =
                *(short8*)&Vt[dv * 40 + seg * 8];
        }
    }
}

// ---------------------------------------------------------------------------
// KL: l_n row sums via SYMMETRIC 128x128 S-tiles; only jt >= it computed.
// Round-3 proven version (pad 72, k-split staging). LDS 36864 -> 4 blocks/CU.
// ---------------------------------------------------------------------------
__global__ __launch_bounds__(256, 4) void kl_sum(
    const ushort* __restrict__ Q,   // [B][N][D] bf16
    float* __restrict__ lsum)       // [B][N]
{
    int pid = blockIdx.x;  // 0..135
    const int b = blockIdx.y;
    int it = 0;
    while (pid >= (16 - it)) { pid -= (16 - it); it++; }
    const int jt = it + pid;
    const int i0 = it * 128, j0 = jt * 128;
    const int t = threadIdx.x;
    const int lane = t & 63, w = t >> 6, l15 = lane & 15, quad = lane >> 4;
    const int wi = (w >> 1) * 64, wj = (w & 1) * 64;

    __shared__ __attribute__((aligned(16))) ushort Qi[128 * 72];
    __shared__ __attribute__((aligned(16))) ushort Qj[128 * 72];

    const ushort* Qb = Q + b * (NN * DD);

    floatx4 acc[4][4];
#pragma unroll
    for (int i = 0; i < 4; i++)
#pragma unroll
        for (int j = 0; j < 4; j++) acc[i][j] = (floatx4)(0.0f);

    for (int kh = 0; kh < 2; kh++) {
        if (kh) __syncthreads();
#pragma unroll
        for (int rep = 0; rep < 4; rep++) {
            int idx = rep * 256 + t;
            int row = idx >> 3, g = idx & 7;
            *(short8*)&Qi[row * 72 + g * 8] = *(const short8*)&Qb[(i0 + row) * DD + kh * 64 + g * 8];
            *(short8*)&Qj[row * 72 + g * 8] = *(const short8*)&Qb[(j0 + row) * DD + kh * 64 + g * 8];
        }
        __syncthreads();

#pragma unroll
        for (int kd = 0; kd < 2; kd++) {
            short8 afr[4], bfr[4];
#pragma unroll
            for (int nt = 0; nt < 4; nt++)
                afr[nt] = *(short8*)&Qi[(wi + nt * 16 + l15) * 72 + kd * 32 + quad * 8];
#pragma unroll
            for (int mt = 0; mt < 4; mt++)
                bfr[mt] = *(short8*)&Qj[(wj + mt * 16 + l15) * 72 + kd * 32 + quad * 8];
#pragma unroll
            for (int nt = 0; nt < 4; nt++)
#pragma unroll
                for (int mt = 0; mt < 4; mt++)
                    acc[nt][mt] = __builtin_amdgcn_mfma_f32_16x16x32_bf16(afr[nt], bfr[mt], acc[nt][mt], 0, 0, 0);
        }
    }

    float cs[4] = {0.f, 0.f, 0.f, 0.f};
#pragma unroll
    for (int nt = 0; nt < 4; nt++) {
        float rs[4] = {0.f, 0.f, 0.f, 0.f};
#pragma unroll
        for (int mt = 0; mt < 4; mt++)
#pragma unroll
            for (int r = 0; r < 4; r++) {
                float p = __expf(acc[nt][mt][r] * RSCALE);
                rs[r] += p;
                cs[mt] += p;
            }
#pragma unroll
        for (int r = 0; r < 4; r++) {
            float s = rs[r];
            s += __shfl_xor(s, 1);
            s += __shfl_xor(s, 2);
            s += __shfl_xor(s, 4);
            s += __shfl_xor(s, 8);
            if (l15 == 0)
                atomicAdd(&lsum[b * NN + i0 + wi + nt * 16 + quad * 4 + r], s);
        }
    }
    if (it != jt) {
#pragma unroll
        for (int mt = 0; mt < 4; mt++) {
            float s = cs[mt];
            s += __shfl_xor(s, 16);
            s += __shfl_xor(s, 32);
            if (lane < 16)
                atomicAdd(&lsum[b * NN + j0 + wj + mt * 16 + l15], s);
        }
    }
}

// ---------------------------------------------------------------------------
// K3: FUSED attention, SWAPPED-S + register PV (no Ps buffer, 2 barriers/iter).
// S computed as mfma(Qn-frag, Qm-frag) -> lane holds P[n=quad*4+r][m=l15+16ms],
// which IS the B-operand layout of mfma_f32_16x16x16_bf16 (k=quad*4+j,col=l15).
// Each wave PVs its own 16-n band over the FULL 128d x 32m tile; block-level
// LDS f32 reduce, then 2-contrib global atomic epilogue (pre-zeroed out).
// LDS: Qm 8704 | Qn 17408 | Vs 18432 = 44544 -> 3 blocks/CU.
// ---------------------------------------------------------------------------
__global__ __launch_bounds__(256) void k_fused(
    const ushort* __restrict__ Q,   // [B][N][D] bf16
    const ushort* __restrict__ VT,  // [B][D][N] bf16 (unscaled, +bias)
    const float* __restrict__ lsum, // [B][N]
    float* __restrict__ out)        // [B][D][N] fp32 (pre-zeroed)
{
    const int mt = blockIdx.x;  // 0..63
    const int h  = blockIdx.y;  // 0..1
    const int b  = blockIdx.z;
    const int m0 = mt * 32;
    const int t = threadIdx.x;
    const int lane = t & 63, w = t >> 6, l15 = lane & 15, quad = lane >> 4;

    __shared__ __attribute__((aligned(16))) char smem[44544];
    ushort* Qm = (ushort*)smem;            // [32][136]
    ushort* Qn = (ushort*)(smem + 8704);   // [64][136]
    ushort* Vs = (ushort*)(smem + 26112);  // [128][72]

    const ushort* Qb = Q + b * (NN * DD);
    const ushort* VTb = VT + (size_t)b * DD * NN;
    const float* lb = lsum + b * NN;

    // stage Qm (32 rows x 128 d) into its persistent buffer
#pragma unroll
    for (int rep = 0; rep < 2; rep++) {
        int idx = rep * 256 + t;
        int row = idx >> 4, g = idx & 15;
        *(short8*)&Qm[row * 136 + g * 8] = *(const short8*)&Qb[(m0 + row) * DD + g * 8];
    }

    floatx4 acc[8][2];
#pragma unroll
    for (int i = 0; i < 8; i++)
#pragma unroll
        for (int j = 0; j < 2; j++) acc[i][j] = (floatx4)(0.0f);

    // per-thread staging coordinates
    const int qsr = t >> 4, qsg = t & 15;   // Qn: row sub, 16B chunk
    const int vsd = t >> 3, vsg = t & 7;    // Vs: d sub, 16B chunk

    short8 qr[4], vr[4];  // in-flight next tile (T14)

#define LOADR(NC)                                                              \
    do {                                                                       \
        _Pragma("unroll")                                                      \
        for (int rep = 0; rep < 4; rep++)                                      \
            qr[rep] = *(const short8*)&Qb[((NC) + rep * 16 + qsr) * DD + qsg * 8]; \
        _Pragma("unroll")                                                      \
        for (int rep = 0; rep < 4; rep++)                                      \
            vr[rep] = *(const short8*)&VTb[(size_t)(rep * 32 + vsd) * NN + (NC) + vsg * 8]; \
    } while (0)

    const int nbeg = h * (NN / 2), nend = nbeg + (NN / 2);

    LOADR(nbeg);  // prologue fetch

    for (int n0c = nbeg; n0c < nend; n0c += 64) {
        // normalizers for this wave's n-band, per accumulator row r
        float4 lb4 = *(const float4*)&lb[n0c + w * 16 + quad * 4];
        __syncthreads();  // prior iter's reads (and Qm stage) complete
        // drain prefetched tile to LDS
#pragma unroll
        for (int rep = 0; rep < 4; rep++)
            *(short8*)&Qn[(rep * 16 + qsr) * 136 + qsg * 8] = qr[rep];
#pragma unroll
        for (int rep = 0; rep < 4; rep++)
            *(short8*)&Vs[(rep * 32 + vsd) * 72 + vsg * 8] = vr[rep];
        __syncthreads();  // tile visible

        // issue next tile's global loads; they ride under S+PV compute
        if (n0c + 64 < nend) LOADR(n0c + 64);

        // --- S stage (swapped): D[n][m] = mfma(A=Qn rows n, B=Qm cols m) ---
        short8 bq[4];
#pragma unroll
        for (int kd = 0; kd < 4; kd++)
            bq[kd] = *(short8*)&Qn[(w * 16 + l15) * 136 + kd * 32 + quad * 8];

        float linv0 = __builtin_amdgcn_rcpf(lb4.x);
        float linv1 = __builtin_amdgcn_rcpf(lb4.y);
        float linv2 = __builtin_amdgcn_rcpf(lb4.z);
        float linv3 = __builtin_amdgcn_rcpf(lb4.w);

        short4v pas[2];
#pragma unroll
        for (int ms = 0; ms < 2; ms++) {
            floatx4 s = (floatx4)(0.0f);
#pragma unroll
            for (int kd = 0; kd < 4; kd++) {
                short8 qmf = *(short8*)&Qm[(ms * 16 + l15) * 136 + kd * 32 + quad * 8];
                s = __builtin_amdgcn_mfma_f32_16x16x32_bf16(bq[kd], qmf, s, 0, 0, 0);
            }
            short4v pa;
            pa[0] = (short)f2bf(__expf(s[0] * RSCALE) * linv0);
            pa[1] = (short)f2bf(__expf(s[1] * RSCALE) * linv1);
            pa[2] = (short)f2bf(__expf(s[2] * RSCALE) * linv2);
            pa[3] = (short)f2bf(__expf(s[3] * RSCALE) * linv3);
            pas[ms] = pa;
        }

        // --- PV stage: each wave, its own 16-n band, full 128d x 32m ---
#pragma unroll
        for (int dt = 0; dt < 8; dt++) {
            short4v va = *(short4v*)&Vs[(dt * 16 + l15) * 72 + w * 16 + quad * 4];
            acc[dt][0] = __builtin_amdgcn_mfma_f32_16x16x16bf16_1k(va, pas[0], acc[dt][0], 0, 0, 0);
            acc[dt][1] = __builtin_amdgcn_mfma_f32_16x16x16bf16_1k(va, pas[1], acc[dt][1], 0, 0, 0);
        }
    }
#undef LOADR

    // --- block-level reduce: 4 waves' [128][32] partials via LDS f32 adds ---
    __syncthreads();
    float* Os = (float*)smem;  // [128][34] pad, 17408 B (over Qm+Qn region)
#pragma unroll
    for (int k = 0; k < 17; k++) Os[k * 256 + t] = 0.0f;
    __syncthreads();
#pragma unroll
    for (int dt = 0; dt < 8; dt++)
#pragma unroll
        for (int ms = 0; ms < 2; ms++)
#pragma unroll
            for (int r = 0; r < 4; r++)
                atomicAdd(&Os[(dt * 16 + quad * 4 + r) * 34 + ms * 16 + l15], acc[dt][ms][r]);
    __syncthreads();

    // epilogue: 2 global atomic contribs/element (h halves), coalesced
    float* ob = out + (size_t)b * DD * NN;
#pragma unroll
    for (int k = 0; k < 16; k++) {
        int idx = k * 256 + t;
        int d = idx >> 5, m = idx & 31;
        atomicAdd(&ob[(size_t)d * NN + m0 + m], Os[d * 34 + m]);
    }
}

// ---------------------------------------------------------------------------
// Fallback path (small ws) — round-3 proven kernels
// ---------------------------------------------------------------------------
__global__ __launch_bounds__(256) void k1_fb(
    const float* __restrict__ x, const float* __restrict__ wqk,
    const float* __restrict__ wv, const float* __restrict__ bv,
    ushort* __restrict__ Q, ushort* __restrict__ V)
{
    const int nt = blockIdx.x;
    const int b  = blockIdx.y;
    const int n0 = nt * 32;
    const int t = threadIdx.x;
    const int lane = t & 63, w = t >> 6, l15 = lane & 15, quad = lane >> 4;

    __shared__ __attribute__((aligned(16))) ushort As[32 * 40];
    __shared__ __attribute__((aligned(16))) ushort Bs[256 * 40];

    floatx4 acc[2][4];
#pragma unroll
    for (int i = 0; i < 2; i++)
#pragma unroll
        for (int j = 0; j < 4; j++) acc[i][j] = (floatx4)(0.0f);

    const float* xb = x + b * (CH * NN) + n0;

    for (int c0 = 0; c0 < CH; c0 += 32) {
        {
            int n = t & 31, g = t >> 5;
            short4v v;
#pragma unroll
            for (int i = 0; i < 4; i++)
                v[i] = (short)f2bf(xb[(c0 + g * 4 + i) * NN + n]);
            *(short4v*)&As[n * 40 + g * 4] = v;
        }
#pragma unroll
        for (int rep = 0; rep < 16; rep++) {
            int idx = rep * 256 + t;
            int row = idx >> 4, cp = idx & 15;
            const float* wf = (row < 128) ? (wqk + row * CH) : (wv + (row - 128) * CH);
            uint pack = (uint)f2bf(wf[c0 + cp * 2]) | ((uint)f2bf(wf[c0 + cp * 2 + 1]) << 16);
            *(uint*)&Bs[row * 40 + cp * 2] = pack;
        }
        __syncthreads();
        short8 a0 = *(short8*)&As[(l15) * 40 + quad * 8];
        short8 a1 = *(short8*)&As[(16 + l15) * 40 + quad * 8];
#pragma unroll
        for (int dt2 = 0; dt2 < 4; dt2++) {
            short8 bf = *(short8*)&Bs[(w * 64 + dt2 * 16 + l15) * 40 + quad * 8];
            acc[0][dt2] = __builtin_amdgcn_mfma_f32_16x16x32_bf16(a0, bf, acc[0][dt2], 0, 0, 0);
            acc[1][dt2] = __builtin_amdgcn_mfma_f32_16x16x32_bf16(a1, bf, acc[1][dt2], 0, 0, 0);
        }
        __syncthreads();
    }
#pragma unroll
    for (int ns = 0; ns < 2; ns++)
#pragma unroll
        for (int dt2 = 0; dt2 < 4; dt2++) {
            int ds_ = w * 64 + dt2 * 16 + l15;
#pragma unroll
            for (int r = 0; r < 4; r++) {
                int n = n0 + ns * 16 + quad * 4 + r;
                float val = acc[ns][dt2][r];
                if (ds_ < 128) {
                    Q[b * (NN * DD) + n * DD + ds_] = f2bf(val);
                } else {
                    int dv = ds_ - 128;
                    V[b * (NN * DD) + n * DD + dv] = f2bf(val + bv[dv]);
                }
            }
        }
}

__global__ __launch_bounds__(256) void k2_norm(
    const ushort* __restrict__ Q, ushort* __restrict__ V)
{
    const int ntile = blockIdx.x;
    const int b = blockIdx.y;
    const int n0 = ntile * 64;
    const int t = threadIdx.x;
    const int lane = t & 63, w = t >> 6, l15 = lane & 15, quad = lane >> 4;

    __shared__ __attribute__((aligned(16))) ushort Qs[64 * 136];
    __shared__ __attribute__((aligned(16))) ushort Qm2[64 * 136];

    const ushort* Qb = Q + b * (NN * DD);

#pragma unroll
    for (int rep = 0; rep < 16; rep++) {
        int idx = rep * 256 + t;
        int row = idx >> 6, dp = idx & 63;
        *(uint*)&Qs[row * 136 + dp * 2] = *(const uint*)&Qb[(n0 + row) * DD + dp * 2];
    }
    __syncthreads();

    short8 afr[4];
#pragma unroll
    for (int kd = 0; kd < 4; kd++)
        afr[kd] = *(short8*)&Qs[(w * 16 + l15) * 136 + kd * 32 + quad * 8];

    float sums[4] = {0.f, 0.f, 0.f, 0.f};

    for (int m0 = 0; m0 < NN; m0 += 64) {
#pragma unroll
        for (int rep = 0; rep < 16; rep++) {
            int idx = rep * 256 + t;
            int row = idx >> 6, dp = idx & 63;
            *(uint*)&Qm2[row * 136 + dp * 2] = *(const uint*)&Qb[(m0 + row) * DD + dp * 2];
        }
        __syncthreads();
#pragma unroll
        for (int ct = 0; ct < 4; ct++) {
            floatx4 s = (floatx4)(0.0f);
#pragma unroll
            for (int kd = 0; kd < 4; kd++) {
                short8 bf = *(short8*)&Qm2[(ct * 16 + l15) * 136 + kd * 32 + quad * 8];
                s = __builtin_amdgcn_mfma_f32_16x16x32_bf16(afr[kd], bf, s, 0, 0, 0);
            }
#pragma unroll
            for (int r = 0; r < 4; r++)
                sums[r] += __expf(s[r] * RSCALE);
        }
        __syncthreads();
    }

#pragma unroll
    for (int r = 0; r < 4; r++) {
        float s = sums[r];
        s += __shfl_xor(s, 1);
        s += __shfl_xor(s, 2);
        s += __shfl_xor(s, 4);
        s += __shfl_xor(s, 8);
        sums[r] = s;
    }

    ushort* Vb = V + b * (NN * DD);
#pragma unroll
    for (int r = 0; r < 4; r++) {
        int n = n0 + w * 16 + quad * 4 + r;
        float inv = 1.0f / sums[r];
        short8 vv = *(short8*)&Vb[n * DD + l15 * 8];
        short8 o;
#pragma unroll
        for (int i = 0; i < 8; i++)
            o[i] = (short)f2bf(bf2f((ushort)vv[i]) * inv);
        *(short8*)&Vb[n * DD + l15 * 8] = o;
    }
}

__global__ __launch_bounds__(256) void k3_attn(
    const ushort* __restrict__ Q, const ushort* __restrict__ Vp,
    float* __restrict__ out)
{
    const int mtile = blockIdx.x;
    const int b = blockIdx.y;
    const int m0 = mtile * 64;
    const int t = threadIdx.x;
    const int lane = t & 63, w = t >> 6, l15 = lane & 15, quad = lane >> 4;

    __shared__ __attribute__((aligned(16))) ushort Qs[64 * 136];
    __shared__ __attribute__((aligned(16))) ushort Qn2[32 * 136];
    __shared__ __attribute__((aligned(16))) ushort Vs2[128 * 40];
    __shared__ __attribute__((aligned(16))) ushort Ps2[64 * 40];

    const ushort* Qb = Q + b * (NN * DD);
    const ushort* Vpb = Vp + b * (NN * DD);

#pragma unroll
    for (int rep = 0; rep < 16; rep++) {
        int idx = rep * 256 + t;
        int row = idx >> 6, dp = idx & 63;
        *(uint*)&Qs[row * 136 + dp * 2] = *(const uint*)&Qb[(m0 + row) * DD + dp * 2];
    }
    __syncthreads();

    short8 afr[4];
#pragma unroll
    for (int kd = 0; kd < 4; kd++)
        afr[kd] = *(short8*)&Qs[(w * 16 + l15) * 136 + kd * 32 + quad * 8];

    floatx4 acc[2][4];
#pragma unroll
    for (int s = 0; s < 2; s++)
#pragma unroll
        for (int mt = 0; mt < 4; mt++) acc[s][mt] = (floatx4)(0.0f);

    for (int n0c = 0; n0c < NN; n0c += 32) {
#pragma unroll
        for (int rep = 0; rep < 8; rep++) {
            int idx = rep * 256 + t;
            int row = idx >> 6, dp = idx & 63;
            *(uint*)&Qn2[row * 136 + dp * 2] = *(const uint*)&Qb[(n0c + row) * DD + dp * 2];
        }
#pragma unroll
        for (int rep = 0; rep < 8; rep++) {
            int idx = rep * 256 + t;
            int np = idx >> 7, d = idx & 127;
            uint v0 = Vpb[(n0c + np * 2) * DD + d];
            uint v1 = Vpb[(n0c + np * 2 + 1) * DD + d];
            *(uint*)&Vs2[d * 40 + np * 2] = v0 | (v1 << 16);
        }
        __syncthreads();

#pragma unroll
        for (int nt2 = 0; nt2 < 2; nt2++) {
            floatx4 s = (floatx4)(0.0f);
#pragma unroll
            for (int kd = 0; kd < 4; kd++) {
                short8 bf = *(short8*)&Qn2[(nt2 * 16 + l15) * 136 + kd * 32 + quad * 8];
                s = __builtin_amdgcn_mfma_f32_16x16x32_bf16(afr[kd], bf, s, 0, 0, 0);
            }
#pragma unroll
            for (int r = 0; r < 4; r++) {
                float p = __expf(s[r] * RSCALE);
                Ps2[(w * 16 + quad * 4 + r) * 40 + nt2 * 16 + l15] = f2bf(p);
            }
        }
        __syncthreads();

        short8 pb[4];
#pragma unroll
        for (int mt = 0; mt < 4; mt++)
            pb[mt] = *(short8*)&Ps2[(mt * 16 + l15) * 40 + quad * 8];
#pragma unroll
        for (int sub = 0; sub < 2; sub++) {
            short8 va = *(short8*)&Vs2[(w * 32 + sub * 16 + l15) * 40 + quad * 8];
#pragma unroll
            for (int mt = 0; mt < 4; mt++)
                acc[sub][mt] = __builtin_amdgcn_mfma_f32_16x16x32_bf16(va, pb[mt], acc[sub][mt], 0, 0, 0);
        }
        __syncthreads();
    }

    float* ob = out + (size_t)b * DD * NN;
#pragma unroll
    for (int sub = 0; sub < 2; sub++)
#pragma unroll
        for (int mt = 0; mt < 4; mt++)
#pragma unroll
            for (int r = 0; r < 4; r++) {
                int d = w * 32 + sub * 16 + quad * 4 + r;
                int m = m0 + mt * 16 + l15;
                ob[(size_t)d * NN + m] = acc[sub][mt][r];
            }
}

extern "C" void kernel_launch(void* const* d_in, const int* in_sizes, int n_in,
                              void* d_out, int out_size, void* d_ws, size_t ws_size,
                              hipStream_t stream) {
    const float* x   = (const float*)d_in[0];
    const float* wqk = (const float*)d_in[1];
    const float* wv  = (const float*)d_in[2];
    const float* bv  = (const float*)d_in[3];
    float* out = (float*)d_out;

    // ws: Q [0,4M) | VT [4M,8M) | Wbf @8M (256K) | lsum @8M+256K (64K)
    ushort* Q = (ushort*)d_ws;

    if (ws_size >= (size_t)33 * 1024 * 1024) {
        ushort* VT   = (ushort*)((char*)d_ws + (4u << 20));
        ushort* Wbf  = (ushort*)((char*)d_ws + (8u << 20));
        float*  lsum = (float*)((char*)d_ws + (8u << 20) + (256u << 10));

        k0_prep<<<512, 256, 0, stream>>>(wqk, wv, Wbf, lsum, out);
        k1_proj<<<dim3(64, 2, 8), 256, 0, stream>>>(x, Wbf, bv, Q, VT);
        kl_sum<<<dim3(136, 8), 256, 0, stream>>>(Q, lsum);
        k_fused<<<dim3(64, 2, 8), 256, 0, stream>>>(Q, VT, lsum, out);
    } else {
        ushort* V = (ushort*)((char*)d_ws + (4u << 20));
        k1_fb<<<dim3(64, 8), 256, 0, stream>>>(x, wqk, wv, bv, Q, V);
        k2_norm<<<dim3(32, 8), 256, 0, stream>>>(Q, V);
        k3_attn<<<dim3(32, 8), 256, 0, stream>>>(Q, V, out);
    }
}

// Round 7
// 154.798 us; speedup vs baseline: 1.5422x; 1.5422x over previous
//
#include <hip/hip_runtime.h>

typedef short short4v __attribute__((ext_vector_type(4)));
typedef short short8 __attribute__((ext_vector_type(8)));
typedef float floatx4 __attribute__((ext_vector_type(4)));
typedef unsigned int uint;
typedef unsigned short ushort;

#define CH 512
#define NN 2048
#define DD 128
#define RSCALE 0.08838834764831845f  // 1/sqrt(128)

__device__ __forceinline__ float bf2f(ushort u) {
    union { uint i; float f; } v; v.i = ((uint)u) << 16; return v.f;
}
__device__ __forceinline__ ushort f2bf(float f) {
    union { float f; uint u; } v; v.f = f;
    uint u = v.u;
    return (ushort)((u + 0x7fffu + ((u >> 16) & 1u)) >> 16);
}

// ---------------------------------------------------------------------------
// K0: weights -> bf16 AND zero lsum AND zero out (merged; one launch).
// ---------------------------------------------------------------------------
__global__ __launch_bounds__(256) void k0_prep(
    const float* __restrict__ wqk, const float* __restrict__ wv,
    ushort* __restrict__ Wbf, float* __restrict__ lsum,
    float* __restrict__ out)
{
    int gid = blockIdx.x * 256 + threadIdx.x;
    if (gid < 32768) {
        int base = gid * 4;
        const float* src = (base < 65536) ? (wqk + base) : (wv + base - 65536);
        float4 v = *(const float4*)src;
        short4v o;
        o[0] = (short)f2bf(v.x); o[1] = (short)f2bf(v.y);
        o[2] = (short)f2bf(v.z); o[3] = (short)f2bf(v.w);
        *(short4v*)&Wbf[base] = o;
    }
    if (gid < 16384) lsum[gid] = 0.0f;
    float4 z; z.x = 0.f; z.y = 0.f; z.z = 0.f; z.w = 0.f;
#pragma unroll
    for (int i = 0; i < 4; i++)
        *(float4*)&out[(size_t)(gid + i * 131072) * 4] = z;
}

// ---------------------------------------------------------------------------
// K1: projections, d-stack split across h; c-step 64 (8 iterations).
// Grid (64 nt, 2 h, 8 b) = 1024 blocks. LDS 33280 -> 4 blocks/CU.
// ---------------------------------------------------------------------------
__global__ __launch_bounds__(256) void k1_proj(
    const float* __restrict__ x,
    const ushort* __restrict__ Wbf,
    const float* __restrict__ bv,
    ushort* __restrict__ Q,
    ushort* __restrict__ VT)
{
    const int nt = blockIdx.x;   // 0..63
    const int h  = blockIdx.y;   // 0..1 (0: Q rows, 1: V rows)
    const int b  = blockIdx.z;   // 0..7
    const int n0 = nt * 32;
    const int t = threadIdx.x;
    const int lane = t & 63, w = t >> 6, l15 = lane & 15, quad = lane >> 4;

    __shared__ __attribute__((aligned(16))) ushort As[32 * 72];
    __shared__ __attribute__((aligned(16))) ushort Bs[128 * 72];
    __shared__ __attribute__((aligned(16))) ushort Vt[128 * 40];

    floatx4 acc[2][2];
#pragma unroll
    for (int i = 0; i < 2; i++)
#pragma unroll
        for (int j = 0; j < 2; j++) acc[i][j] = (floatx4)(0.0f);

    const float* xb = x + b * (CH * NN) + n0;
    const ushort* Wh = Wbf + h * 128 * CH;

    const int an = t & 31, ag = t >> 5;       // A-stage: n, c-chunk (0..7)

    for (int c0 = 0; c0 < CH; c0 += 64) {
        // stage A: [32 n][64 c], fp32 -> bf16, 8 elems/thread
        {
            short8 v;
#pragma unroll
            for (int i = 0; i < 8; i++)
                v[i] = (short)f2bf(xb[(c0 + ag * 8 + i) * NN + an]);
            *(short8*)&As[an * 72 + ag * 8] = v;
        }
        // stage B: [128 rows][64 c], 4 x b128/thread
#pragma unroll
        for (int rep = 0; rep < 4; rep++) {
            int idx = rep * 256 + t;
            int row = idx >> 3, g = idx & 7;
            *(short8*)&Bs[row * 72 + g * 8] = *(const short8*)&Wh[row * CH + c0 + g * 8];
        }
        __syncthreads();
#pragma unroll
        for (int kd = 0; kd < 2; kd++) {
            short8 a0 = *(short8*)&As[(l15) * 72 + kd * 32 + quad * 8];
            short8 a1 = *(short8*)&As[(16 + l15) * 72 + kd * 32 + quad * 8];
#pragma unroll
            for (int dt2 = 0; dt2 < 2; dt2++) {
                short8 bf = *(short8*)&Bs[(w * 32 + dt2 * 16 + l15) * 72 + kd * 32 + quad * 8];
                acc[0][dt2] = __builtin_amdgcn_mfma_f32_16x16x32_bf16(a0, bf, acc[0][dt2], 0, 0, 0);
                acc[1][dt2] = __builtin_amdgcn_mfma_f32_16x16x32_bf16(a1, bf, acc[1][dt2], 0, 0, 0);
            }
        }
        __syncthreads();
    }

    // epilogue
#pragma unroll
    for (int ns = 0; ns < 2; ns++)
#pragma unroll
        for (int dt2 = 0; dt2 < 2; dt2++) {
            int ds_ = w * 32 + dt2 * 16 + l15;  // 0..127
#pragma unroll
            for (int r = 0; r < 4; r++) {
                int nl = ns * 16 + quad * 4 + r;
                float val = acc[ns][dt2][r];
                if (h == 0) {
                    Q[b * (NN * DD) + (n0 + nl) * DD + ds_] = f2bf(val);
                } else {
                    Vt[ds_ * 40 + nl] = f2bf(val + bv[ds_]);
                }
            }
        }
    if (h == 1) {
        __syncthreads();
#pragma unroll
        for (int rep = 0; rep < 2; rep++) {
            int idx = rep * 256 + t;
            int dv = idx >> 2, seg = idx & 3;
            *(short8*)&VT[((size_t)b * DD + dv) * NN + n0 + seg * 8] =
                *(short8*)&Vt[dv * 40 + seg * 8];
        }
    }
}

// ---------------------------------------------------------------------------
// KL: l_n row sums via SYMMETRIC 128x128 S-tiles; only jt >= it computed.
// Proven round-3 version (pad 72, k-split staging). LDS 36864 -> 4 blocks/CU.
// ---------------------------------------------------------------------------
__global__ __launch_bounds__(256, 4) void kl_sum(
    const ushort* __restrict__ Q,   // [B][N][D] bf16
    float* __restrict__ lsum)       // [B][N]
{
    int pid = blockIdx.x;  // 0..135
    const int b = blockIdx.y;
    int it = 0;
    while (pid >= (16 - it)) { pid -= (16 - it); it++; }
    const int jt = it + pid;
    const int i0 = it * 128, j0 = jt * 128;
    const int t = threadIdx.x;
    const int lane = t & 63, w = t >> 6, l15 = lane & 15, quad = lane >> 4;
    const int wi = (w >> 1) * 64, wj = (w & 1) * 64;

    __shared__ __attribute__((aligned(16))) ushort Qi[128 * 72];
    __shared__ __attribute__((aligned(16))) ushort Qj[128 * 72];

    const ushort* Qb = Q + b * (NN * DD);

    floatx4 acc[4][4];
#pragma unroll
    for (int i = 0; i < 4; i++)
#pragma unroll
        for (int j = 0; j < 4; j++) acc[i][j] = (floatx4)(0.0f);

    for (int kh = 0; kh < 2; kh++) {
        if (kh) __syncthreads();
#pragma unroll
        for (int rep = 0; rep < 4; rep++) {
            int idx = rep * 256 + t;
            int row = idx >> 3, g = idx & 7;
            *(short8*)&Qi[row * 72 + g * 8] = *(const short8*)&Qb[(i0 + row) * DD + kh * 64 + g * 8];
            *(short8*)&Qj[row * 72 + g * 8] = *(const short8*)&Qb[(j0 + row) * DD + kh * 64 + g * 8];
        }
        __syncthreads();

#pragma unroll
        for (int kd = 0; kd < 2; kd++) {
            short8 afr[4], bfr[4];
#pragma unroll
            for (int nt = 0; nt < 4; nt++)
                afr[nt] = *(short8*)&Qi[(wi + nt * 16 + l15) * 72 + kd * 32 + quad * 8];
#pragma unroll
            for (int mt = 0; mt < 4; mt++)
                bfr[mt] = *(short8*)&Qj[(wj + mt * 16 + l15) * 72 + kd * 32 + quad * 8];
#pragma unroll
            for (int nt = 0; nt < 4; nt++)
#pragma unroll
                for (int mt = 0; mt < 4; mt++)
                    acc[nt][mt] = __builtin_amdgcn_mfma_f32_16x16x32_bf16(afr[nt], bfr[mt], acc[nt][mt], 0, 0, 0);
        }
    }

    float cs[4] = {0.f, 0.f, 0.f, 0.f};
#pragma unroll
    for (int nt = 0; nt < 4; nt++) {
        float rs[4] = {0.f, 0.f, 0.f, 0.f};
#pragma unroll
        for (int mt = 0; mt < 4; mt++)
#pragma unroll
            for (int r = 0; r < 4; r++) {
                float p = __expf(acc[nt][mt][r] * RSCALE);
                rs[r] += p;
                cs[mt] += p;
            }
#pragma unroll
        for (int r = 0; r < 4; r++) {
            float s = rs[r];
            s += __shfl_xor(s, 1);
            s += __shfl_xor(s, 2);
            s += __shfl_xor(s, 4);
            s += __shfl_xor(s, 8);
            if (l15 == 0)
                atomicAdd(&lsum[b * NN + i0 + wi + nt * 16 + quad * 4 + r], s);
        }
    }
    if (it != jt) {
#pragma unroll
        for (int mt = 0; mt < 4; mt++) {
            float s = cs[mt];
            s += __shfl_xor(s, 16);
            s += __shfl_xor(s, 32);
            if (lane < 16)
                atomicAdd(&lsum[b * NN + j0 + wj + mt * 16 + l15], s);
        }
    }
}

// ---------------------------------------------------------------------------
// K3: FUSED attention — EXACT round-3 structure (proven 46.6us), one change:
// n-split h widened 2 -> 4 (grid 2048, 8 iterations/block). Halves per-block
// serial path; ~3.3 residency rounds let blocks at different phases fill each
// other's barrier/load stalls. 4 fp32 atomic contribs/elem (commutative;
// order noise ~1e-6 << 0.03 margin). LDS 40192 -> 4 blocks/CU.
// ---------------------------------------------------------------------------
__global__ __launch_bounds__(256, 4) void k_fused(
    const ushort* __restrict__ Q,   // [B][N][D] bf16
    const ushort* __restrict__ VT,  // [B][D][N] bf16 (unscaled, +bias)
    const float* __restrict__ lsum, // [B][N]
    float* __restrict__ out)        // [B][D][N] fp32 (pre-zeroed)
{
    const int mt = blockIdx.x;  // 0..63
    const int h  = blockIdx.y;  // 0..3
    const int b  = blockIdx.z;
    const int m0 = mt * 32;
    const int t = threadIdx.x;
    const int lane = t & 63, w = t >> 6, l15 = lane & 15, quad = lane >> 4;

    __shared__ __attribute__((aligned(16))) ushort Qn[64 * 136];
    __shared__ __attribute__((aligned(16))) ushort Vs[128 * 72];
    __shared__ __attribute__((aligned(16))) ushort Ps[32 * 68];

    const ushort* Qb = Q + b * (NN * DD);
    const ushort* VTb = VT + (size_t)b * DD * NN;
    const float* lb = lsum + b * NN;

    // stage Qm (32 rows x 128 d) through Qn rows 0..31, hoist to regs
#pragma unroll
    for (int rep = 0; rep < 2; rep++) {
        int idx = rep * 256 + t;
        int row = idx >> 4, g = idx & 15;
        *(short8*)&Qn[row * 136 + g * 8] = *(const short8*)&Qb[(m0 + row) * DD + g * 8];
    }
    __syncthreads();

    short8 qm[2][4];
#pragma unroll
    for (int ms = 0; ms < 2; ms++)
#pragma unroll
        for (int kd = 0; kd < 4; kd++)
            qm[ms][kd] = *(short8*)&Qn[(ms * 16 + l15) * 136 + kd * 32 + quad * 8];

    floatx4 acc[2][2];
#pragma unroll
    for (int i = 0; i < 2; i++)
#pragma unroll
        for (int j = 0; j < 2; j++) acc[i][j] = (floatx4)(0.0f);

    // per-thread staging coordinates
    const int qsr = t >> 4, qsg = t & 15;   // Qn: row sub (16/rep), 16B chunk
    const int vsd = t >> 3, vsg = t & 7;    // Vs: d sub (32/rep), 16B chunk

    short8 qr[4], vr[4];  // in-flight next tile (T14)

#define LOADR(NC)                                                              \
    do {                                                                       \
        _Pragma("unroll")                                                      \
        for (int rep = 0; rep < 4; rep++)                                      \
            qr[rep] = *(const short8*)&Qb[((NC) + rep * 16 + qsr) * DD + qsg * 8]; \
        _Pragma("unroll")                                                      \
        for (int rep = 0; rep < 4; rep++)                                      \
            vr[rep] = *(const short8*)&VTb[(size_t)(rep * 32 + vsd) * NN + (NC) + vsg * 8]; \
    } while (0)

    const int nbeg = h * (NN / 4), nend = nbeg + (NN / 4);

    LOADR(nbeg);  // prologue fetch

    for (int n0c = nbeg; n0c < nend; n0c += 64) {
        float lw = lb[n0c + w * 16 + l15];  // normalizer for this lane's n-col
        __syncthreads();  // prior iter's reads (and qm hoist) complete
        // drain prefetched tile to LDS
#pragma unroll
        for (int rep = 0; rep < 4; rep++)
            *(short8*)&Qn[(rep * 16 + qsr) * 136 + qsg * 8] = qr[rep];
#pragma unroll
        for (int rep = 0; rep < 4; rep++)
            *(short8*)&Vs[(rep * 32 + vsd) * 72 + vsg * 8] = vr[rep];
        __syncthreads();  // tile visible

        // issue next tile's global loads; they ride under S+PV compute
        if (n0c + 64 < nend) LOADR(n0c + 64);

        // S stage: wave w owns n-band w*16; computes S[32 m][16 n]
        {
            float linv = 1.0f / lw;
            short8 bq[4];
#pragma unroll
            for (int kd = 0; kd < 4; kd++)
                bq[kd] = *(short8*)&Qn[(w * 16 + l15) * 136 + kd * 32 + quad * 8];
#pragma unroll
            for (int ms = 0; ms < 2; ms++) {
                floatx4 s = (floatx4)(0.0f);
#pragma unroll
                for (int kd = 0; kd < 4; kd++)
                    s = __builtin_amdgcn_mfma_f32_16x16x32_bf16(qm[ms][kd], bq[kd], s, 0, 0, 0);
#pragma unroll
                for (int r = 0; r < 4; r++) {
                    float p = __expf(s[r] * RSCALE) * linv;
                    Ps[(ms * 16 + quad * 4 + r) * 68 + w * 16 + l15] = f2bf(p);
                }
            }
        }
        __syncthreads();  // Ps ready

        // PV stage: wave w owns d-band w*32
#pragma unroll
        for (int kn = 0; kn < 2; kn++) {
            short8 va0 = *(short8*)&Vs[(w * 32 + l15) * 72 + kn * 32 + quad * 8];
            short8 va1 = *(short8*)&Vs[(w * 32 + 16 + l15) * 72 + kn * 32 + quad * 8];
#pragma unroll
            for (int mf = 0; mf < 2; mf++) {
                short8 pb = *(short8*)&Ps[(mf * 16 + l15) * 68 + kn * 32 + quad * 8];
                acc[0][mf] = __builtin_amdgcn_mfma_f32_16x16x32_bf16(va0, pb, acc[0][mf], 0, 0, 0);
                acc[1][mf] = __builtin_amdgcn_mfma_f32_16x16x32_bf16(va1, pb, acc[1][mf], 0, 0, 0);
            }
        }
    }
#undef LOADR

    // epilogue: atomic accumulate into out (4 contributions/element total)
    float* ob = out + (size_t)b * DD * NN;
#pragma unroll
    for (int dsub = 0; dsub < 2; dsub++)
#pragma unroll
        for (int mf = 0; mf < 2; mf++)
#pragma unroll
            for (int r = 0; r < 4; r++) {
                int d = w * 32 + dsub * 16 + quad * 4 + r;
                atomicAdd(&ob[(size_t)d * NN + m0 + mf * 16 + l15], acc[dsub][mf][r]);
            }
}

// ---------------------------------------------------------------------------
// Fallback path (small ws) — proven kernels
// ---------------------------------------------------------------------------
__global__ __launch_bounds__(256) void k1_fb(
    const float* __restrict__ x, const float* __restrict__ wqk,
    const float* __restrict__ wv, const float* __restrict__ bv,
    ushort* __restrict__ Q, ushort* __restrict__ V)
{
    const int nt = blockIdx.x;
    const int b  = blockIdx.y;
    const int n0 = nt * 32;
    const int t = threadIdx.x;
    const int lane = t & 63, w = t >> 6, l15 = lane & 15, quad = lane >> 4;

    __shared__ __attribute__((aligned(16))) ushort As[32 * 40];
    __shared__ __attribute__((aligned(16))) ushort Bs[256 * 40];

    floatx4 acc[2][4];
#pragma unroll
    for (int i = 0; i < 2; i++)
#pragma unroll
        for (int j = 0; j < 4; j++) acc[i][j] = (floatx4)(0.0f);

    const float* xb = x + b * (CH * NN) + n0;

    for (int c0 = 0; c0 < CH; c0 += 32) {
        {
            int n = t & 31, g = t >> 5;
            short4v v;
#pragma unroll
            for (int i = 0; i < 4; i++)
                v[i] = (short)f2bf(xb[(c0 + g * 4 + i) * NN + n]);
            *(short4v*)&As[n * 40 + g * 4] = v;
        }
#pragma unroll
        for (int rep = 0; rep < 16; rep++) {
            int idx = rep * 256 + t;
            int row = idx >> 4, cp = idx & 15;
            const float* wf = (row < 128) ? (wqk + row * CH) : (wv + (row - 128) * CH);
            uint pack = (uint)f2bf(wf[c0 + cp * 2]) | ((uint)f2bf(wf[c0 + cp * 2 + 1]) << 16);
            *(uint*)&Bs[row * 40 + cp * 2] = pack;
        }
        __syncthreads();
        short8 a0 = *(short8*)&As[(l15) * 40 + quad * 8];
        short8 a1 = *(short8*)&As[(16 + l15) * 40 + quad * 8];
#pragma unroll
        for (int dt2 = 0; dt2 < 4; dt2++) {
            short8 bf = *(short8*)&Bs[(w * 64 + dt2 * 16 + l15) * 40 + quad * 8];
            acc[0][dt2] = __builtin_amdgcn_mfma_f32_16x16x32_bf16(a0, bf, acc[0][dt2], 0, 0, 0);
            acc[1][dt2] = __builtin_amdgcn_mfma_f32_16x16x32_bf16(a1, bf, acc[1][dt2], 0, 0, 0);
        }
        __syncthreads();
    }
#pragma unroll
    for (int ns = 0; ns < 2; ns++)
#pragma unroll
        for (int dt2 = 0; dt2 < 4; dt2++) {
            int ds_ = w * 64 + dt2 * 16 + l15;
#pragma unroll
            for (int r = 0; r < 4; r++) {
                int n = n0 + ns * 16 + quad * 4 + r;
                float val = acc[ns][dt2][r];
                if (ds_ < 128) {
                    Q[b * (NN * DD) + n * DD + ds_] = f2bf(val);
                } else {
                    int dv = ds_ - 128;
                    V[b * (NN * DD) + n * DD + dv] = f2bf(val + bv[dv]);
                }
            }
        }
}

__global__ __launch_bounds__(256) void k2_norm(
    const ushort* __restrict__ Q, ushort* __restrict__ V)
{
    const int ntile = blockIdx.x;
    const int b = blockIdx.y;
    const int n0 = ntile * 64;
    const int t = threadIdx.x;
    const int lane = t & 63, w = t >> 6, l15 = lane & 15, quad = lane >> 4;

    __shared__ __attribute__((aligned(16))) ushort Qs[64 * 136];
    __shared__ __attribute__((aligned(16))) ushort Qm2[64 * 136];

    const ushort* Qb = Q + b * (NN * DD);

#pragma unroll
    for (int rep = 0; rep < 16; rep++) {
        int idx = rep * 256 + t;
        int row = idx >> 6, dp = idx & 63;
        *(uint*)&Qs[row * 136 + dp * 2] = *(const uint*)&Qb[(n0 + row) * DD + dp * 2];
    }
    __syncthreads();

    short8 afr[4];
#pragma unroll
    for (int kd = 0; kd < 4; kd++)
        afr[kd] = *(short8*)&Qs[(w * 16 + l15) * 136 + kd * 32 + quad * 8];

    float sums[4] = {0.f, 0.f, 0.f, 0.f};

    for (int m0 = 0; m0 < NN; m0 += 64) {
#pragma unroll
        for (int rep = 0; rep < 16; rep++) {
            int idx = rep * 256 + t;
            int row = idx >> 6, dp = idx & 63;
            *(uint*)&Qm2[row * 136 + dp * 2] = *(const uint*)&Qb[(m0 + row) * DD + dp * 2];
        }
        __syncthreads();
#pragma unroll
        for (int ct = 0; ct < 4; ct++) {
            floatx4 s = (floatx4)(0.0f);
#pragma unroll
            for (int kd = 0; kd < 4; kd++) {
                short8 bf = *(short8*)&Qm2[(ct * 16 + l15) * 136 + kd * 32 + quad * 8];
                s = __builtin_amdgcn_mfma_f32_16x16x32_bf16(afr[kd], bf, s, 0, 0, 0);
            }
#pragma unroll
            for (int r = 0; r < 4; r++)
                sums[r] += __expf(s[r] * RSCALE);
        }
        __syncthreads();
    }

#pragma unroll
    for (int r = 0; r < 4; r++) {
        float s = sums[r];
        s += __shfl_xor(s, 1);
        s += __shfl_xor(s, 2);
        s += __shfl_xor(s, 4);
        s += __shfl_xor(s, 8);
        sums[r] = s;
    }

    ushort* Vb = V + b * (NN * DD);
#pragma unroll
    for (int r = 0; r < 4; r++) {
        int n = n0 + w * 16 + quad * 4 + r;
        float inv = 1.0f / sums[r];
        short8 vv = *(short8*)&Vb[n * DD + l15 * 8];
        short8 o;
#pragma unroll
        for (int i = 0; i < 8; i++)
            o[i] = (short)f2bf(bf2f((ushort)vv[i]) * inv);
        *(short8*)&Vb[n * DD + l15 * 8] = o;
    }
}

__global__ __launch_bounds__(256) void k3_attn(
    const ushort* __restrict__ Q, const ushort* __restrict__ Vp,
    float* __restrict__ out)
{
    const int mtile = blockIdx.x;
    const int b = blockIdx.y;
    const int m0 = mtile * 64;
    const int t = threadIdx.x;
    const int lane = t & 63, w = t >> 6, l15 = lane & 15, quad = lane >> 4;

    __shared__ __attribute__((aligned(16))) ushort Qs[64 * 136];
    __shared__ __attribute__((aligned(16))) ushort Qn2[32 * 136];
    __shared__ __attribute__((aligned(16))) ushort Vs2[128 * 40];
    __shared__ __attribute__((aligned(16))) ushort Ps2[64 * 40];

    const ushort* Qb = Q + b * (NN * DD);
    const ushort* Vpb = Vp + b * (NN * DD);

#pragma unroll
    for (int rep = 0; rep < 16; rep++) {
        int idx = rep * 256 + t;
        int row = idx >> 6, dp = idx & 63;
        *(uint*)&Qs[row * 136 + dp * 2] = *(const uint*)&Qb[(m0 + row) * DD + dp * 2];
    }
    __syncthreads();

    short8 afr[4];
#pragma unroll
    for (int kd = 0; kd < 4; kd++)
        afr[kd] = *(short8*)&Qs[(w * 16 + l15) * 136 + kd * 32 + quad * 8];

    floatx4 acc[2][4];
#pragma unroll
    for (int s = 0; s < 2; s++)
#pragma unroll
        for (int mt = 0; mt < 4; mt++) acc[s][mt] = (floatx4)(0.0f);

    for (int n0c = 0; n0c < NN; n0c += 32) {
#pragma unroll
        for (int rep = 0; rep < 8; rep++) {
            int idx = rep * 256 + t;
            int row = idx >> 6, dp = idx & 63;
            *(uint*)&Qn2[row * 136 + dp * 2] = *(const uint*)&Qb[(n0c + row) * DD + dp * 2];
        }
#pragma unroll
        for (int rep = 0; rep < 8; rep++) {
            int idx = rep * 256 + t;
            int np = idx >> 7, d = idx & 127;
            uint v0 = Vpb[(n0c + np * 2) * DD + d];
            uint v1 = Vpb[(n0c + np * 2 + 1) * DD + d];
            *(uint*)&Vs2[d * 40 + np * 2] = v0 | (v1 << 16);
        }
        __syncthreads();

#pragma unroll
        for (int nt2 = 0; nt2 < 2; nt2++) {
            floatx4 s = (floatx4)(0.0f);
#pragma unroll
            for (int kd = 0; kd < 4; kd++) {
                short8 bf = *(short8*)&Qn2[(nt2 * 16 + l15) * 136 + kd * 32 + quad * 8];
                s = __builtin_amdgcn_mfma_f32_16x16x32_bf16(afr[kd], bf, s, 0, 0, 0);
            }
#pragma unroll
            for (int r = 0; r < 4; r++) {
                float p = __expf(s[r] * RSCALE);
                Ps2[(w * 16 + quad * 4 + r) * 40 + nt2 * 16 + l15] = f2bf(p);
            }
        }
        __syncthreads();

        short8 pb[4];
#pragma unroll
        for (int mt = 0; mt < 4; mt++)
            pb[mt] = *(short8*)&Ps2[(mt * 16 + l15) * 40 + quad * 8];
#pragma unroll
        for (int sub = 0; sub < 2; sub++) {
            short8 va = *(short8*)&Vs2[(w * 32 + sub * 16 + l15) * 40 + quad * 8];
#pragma unroll
            for (int mt = 0; mt < 4; mt++)
                acc[sub][mt] = __builtin_amdgcn_mfma_f32_16x16x32_bf16(va, pb[mt], acc[sub][mt], 0, 0, 0);
        }
        __syncthreads();
    }

    float* ob = out + (size_t)b * DD * NN;
#pragma unroll
    for (int sub = 0; sub < 2; sub++)
#pragma unroll
        for (int mt = 0; mt < 4; mt++)
#pragma unroll
            for (int r = 0; r < 4; r++) {
                int d = w * 32 + sub * 16 + quad * 4 + r;
                int m = m0 + mt * 16 + l15;
                ob[(size_t)d * NN + m] = acc[sub][mt][r];
            }
}

extern "C" void kernel_launch(void* const* d_in, const int* in_sizes, int n_in,
                              void* d_out, int out_size, void* d_ws, size_t ws_size,
                              hipStream_t stream) {
    const float* x   = (const float*)d_in[0];
    const float* wqk = (const float*)d_in[1];
    const float* wv  = (const float*)d_in[2];
    const float* bv  = (const float*)d_in[3];
    float* out = (float*)d_out;

    // ws: Q [0,4M) | VT [4M,8M) | Wbf @8M (256K) | lsum @8M+256K (64K)
    ushort* Q = (ushort*)d_ws;

    if (ws_size >= (size_t)33 * 1024 * 1024) {
        ushort* VT   = (ushort*)((char*)d_ws + (4u << 20));
        ushort* Wbf  = (ushort*)((char*)d_ws + (8u << 20));
        float*  lsum = (float*)((char*)d_ws + (8u << 20) + (256u << 10));

        k0_prep<<<512, 256, 0, stream>>>(wqk, wv, Wbf, lsum, out);
        k1_proj<<<dim3(64, 2, 8), 256, 0, stream>>>(x, Wbf, bv, Q, VT);
        kl_sum<<<dim3(136, 8), 256, 0, stream>>>(Q, lsum);
        k_fused<<<dim3(64, 4, 8), 256, 0, stream>>>(Q, VT, lsum, out);
    } else {
        ushort* V = (ushort*)((char*)d_ws + (4u << 20));
        k1_fb<<<dim3(64, 8), 256, 0, stream>>>(x, wqk, wv, bv, Q, V);
        k2_norm<<<dim3(32, 8), 256, 0, stream>>>(Q, V);
        k3_attn<<<dim3(32, 8), 256, 0, stream>>>(Q, V, out);
    }
}